// Round 4
// baseline (302.146 us; speedup 1.0000x reference)
//
#include <hip/hip_runtime.h>

#define N_ROWS 4096
#define IN_F   4096
#define OUT_F  4096
#define C_CB   256
#define KDIM   4096   // C_CB * 16

typedef short bf16x8 __attribute__((ext_vector_type(8)));
typedef float f32x4  __attribute__((ext_vector_type(4)));

union ABFrag { unsigned long long u[2]; bf16x8 v; };

// pack two fp32 -> one dword of 2x bf16 (RNE), a in low half. 2 VALU + 1 v_perm.
__device__ __forceinline__ unsigned int bfpack(float a, float b) {
    unsigned int ua = __builtin_bit_cast(unsigned int, a);
    unsigned int ub = __builtin_bit_cast(unsigned int, b);
    ua += 0x7FFFu + ((ua >> 16) & 1u);
    ub += 0x7FFFu + ((ub >> 16) & 1u);
    return __builtin_amdgcn_perm(ub, ua, 0x07060302u);   // [b.hi16 : a.hi16]
}

// ---------------- Kernel 1: tree descent via LDS-staged gathers ----------------
__global__ __launch_bounds__(256) void k_idx(const float* __restrict__ input,
                                             const int* __restrict__ dims,
                                             const float* __restrict__ thr,
                                             unsigned char* __restrict__ idx4) {
    __shared__ float rowS[IN_F];         // 16 KB
    __shared__ float thrS[C_CB * 15];    // 15 KB
    __shared__ int   dimS[C_CB * 4];     // 4 KB
    const int n = blockIdx.x;
    const int t = threadIdx.x;

    #pragma unroll
    for (int i = 0; i < 4; i++) dimS[i * 256 + t] = dims[i * 256 + t];
    #pragma unroll
    for (int i = 0; i < 15; i++) thrS[i * 256 + t] = thr[i * 256 + t];
    const float* row = input + (size_t)n * IN_F;
    #pragma unroll
    for (int i = 0; i < 4; i++) {
        float4 v = *(const float4*)(row + i * 1024 + t * 4);
        *(float4*)(rowS + i * 1024 + t * 4) = v;
    }
    __syncthreads();

    const int c = t;
    int4 d = *(const int4*)(dimS + c * 4);
    const float* th = thrS + c * 15;
    float x0 = rowS[d.x], x1 = rowS[d.y], x2 = rowS[d.z], x3 = rowS[d.w];
    int b0 = x0 > th[0];
    int j1 = 1 + b0;
    int b1 = x1 > th[j1];
    int j2 = 2 * j1 + 1 + b1;
    int b2 = x2 > th[j2];
    int j3 = 2 * j2 + 1 + b2;
    int b3 = x3 > th[j3];
    int idx = (b0 << 3) | (b1 << 2) | (b2 << 1) | b3;
    int other = __shfl_xor(idx, 1);
    if (!(c & 1))
        idx4[(c >> 1) * N_ROWS + n] = (unsigned char)(idx | (other << 4));
}

// ---------------- Kernel 2: GEMM, fp32 lut staged+converted inline ----------------
// out[n][k] = sum_c lut[k][c][idx[n][c]]
// k_cvt eliminated: B tiles are loaded fp32 -> regs (issued before the MFMA
// cluster), converted to bf16 via v_perm, ds_written after (T14 split).
// M=2 m-tiles per block: each staged B k-tile feeds two 128-row A-idx tiles,
// halving staged bytes + convert VALU per MFMA. Round-2/3 verified schedule
// skeleton (2-deep dbuf, hoisted ds_reads, setprio cluster, 2 barriers/iter).
#define BM 128          // rows per m-tile
#define MT 2            // m-tiles per block (block covers 256 rows)
#define BN 128
#define BKT 64          // kdim per LDS stage (2 MFMA K-steps of 32)
#define BSTAGE (BN * BKT * 2)   // 16 KB per B buffer (bf16 after convert)
#define NT (KDIM / BKT)         // 64 tiles

__global__ __launch_bounds__(256, 2) void k_gemm(const float* __restrict__ lutf,
                                                 const unsigned char* __restrict__ idx4,
                                                 float* __restrict__ out) {
    __shared__ unsigned char smem[32768 + 2 * BSTAGE];   // idx 32KB + 2x B 16KB = 64 KB
    unsigned char* ish  = smem;                          // [cbp 128][row 256]
    unsigned char* bsh0 = smem + 32768;
    unsigned char* bsh1 = smem + 32768 + BSTAGE;

    const int t   = threadIdx.x;
    const int l15 = t & 15;
    const int q   = (t >> 4) & 3;          // quad within wave
    const int w   = t >> 6;
    const int wm  = w >> 1, wn = w & 1;    // 2x2 waves; per m-tile each wave owns 64x64

    // XCD swizzle: XCD = bid&7 owns 4 consecutive n-panels x all m-groups.
    const int bid = blockIdx.x;            // 512 blocks = 32 bx x 16 byp
    const int bx  = ((bid & 7) << 2) | ((bid >> 3) & 3);   // n-block 0..31
    const int byp = bid >> 5;                              // m-group 0..15
    const int m0  = byp * (BM * MT);
    const int n0  = bx * BN;

    // --- idx staging: [cbp 128][row 256] <- idx4[cbp][m0..m0+256) (8 chunks/thread) ---
    auto stageIdx = [&]() {
        #pragma unroll
        for (int qq = 0; qq < 8; qq++) {
            int L = qq * 256 + t;          // chunk: cbp = L>>4, row-part = L&15
            const unsigned char* g = idx4 + (size_t)(L >> 4) * N_ROWS + m0 + (L & 15) * 16;
            __builtin_amdgcn_global_load_lds(
                (const __attribute__((address_space(1))) void*)g,
                (__attribute__((address_space(3))) void*)(ish + L * 16), 16, 0, 0);
        }
    };

    // --- B tile: load 32 fp32/thread to regs (chunk-XOR swizzled position) ---
    auto loadB = [&](float4* ra, int kbn) {
        #pragma unroll
        for (int i = 0; i < 4; i++) {
            int L = i * 256 + t;                // 16B bf16-chunk index in LDS
            int r = L >> 3, p = L & 7;
            int c = p ^ (r & 7);                // global chunk stored at position p
            const float* g = lutf + (size_t)(n0 + r) * KDIM + kbn + c * 8;
            ra[2 * i]     = *(const float4*)g;
            ra[2 * i + 1] = *(const float4*)(g + 4);
        }
    };
    // --- convert 32 fp32 -> 16B bf16 chunks, write to LDS ---
    auto cvtWrite = [&](unsigned char* dst, const float4* ra) {
        #pragma unroll
        for (int i = 0; i < 4; i++) {
            float4 f0 = ra[2 * i], f1 = ra[2 * i + 1];
            uint4 o;
            o.x = bfpack(f0.x, f0.y);
            o.y = bfpack(f0.z, f0.w);
            o.z = bfpack(f1.x, f1.y);
            o.w = bfpack(f1.z, f1.w);
            *(uint4*)(dst + (i * 256 + t) * 16) = o;
        }
    };

    f32x4 acc[MT][4][4];
    #pragma unroll
    for (int mt = 0; mt < MT; mt++)
        #pragma unroll
        for (int mi = 0; mi < 4; mi++)
            #pragma unroll
            for (int ni = 0; ni < 4; ni++)
                acc[mt][mi][ni] = (f32x4){0.f, 0.f, 0.f, 0.f};

    const int xorv = l15 & 7;                       // B chunk swizzle key
    const int bRowByte = (wn * 64 + l15) * (BKT * 2);
    const int aByte = wm * 64 + l15 * 4;            // idx word offset within a cbp row

    const int qh4  = (q >> 1) * 4;                  // nibble select: cb c0 vs c0+1
    const unsigned int sub8 = (q & 1) << 3;         // window offset within codebook

    float4 ra[8];

    // ---- prologue: idx + tiles 0,1 staged ----
    stageIdx();
    loadB(ra, 0);
    asm volatile("s_waitcnt vmcnt(0)" ::: "memory");
    cvtWrite(bsh0, ra);
    loadB(ra, BKT);
    asm volatile("s_waitcnt vmcnt(0)" ::: "memory");
    cvtWrite(bsh1, ra);
    asm volatile("s_waitcnt lgkmcnt(0)" ::: "memory");
    __builtin_amdgcn_s_barrier();
    __builtin_amdgcn_sched_barrier(0);

    for (int tt = 0; tt < NT; tt++) {
        const int kb = tt * BKT;
        unsigned char* cur = (tt & 1) ? bsh1 : bsh0;

        // [A] all LDS->reg reads for this tile (B frags shared across both m-tiles)
        ABFrag bf2[2][4];
        unsigned int w32v[2][MT];
        #pragma unroll
        for (int s = 0; s < 2; s++) {
            const int chunkOff = ((s * 4 + q) ^ xorv) * 16;
            #pragma unroll
            for (int ni = 0; ni < 4; ni++)
                bf2[s][ni].v = *(const bf16x8*)(cur + bRowByte + ni * (16 * BKT * 2) + chunkOff);
            #pragma unroll
            for (int mt = 0; mt < MT; mt++)
                w32v[s][mt] = *(const unsigned int*)(ish + ((kb >> 5) + s) * 256 + mt * 128 + aByte);
        }
        asm volatile("s_waitcnt lgkmcnt(0)" ::: "memory");
        __builtin_amdgcn_sched_barrier(0);
        // [B] all waves done reading cur -> overwrite safe
        __builtin_amdgcn_s_barrier();
        __builtin_amdgcn_sched_barrier(0);
        // [C] issue fp32 loads for tile tt+2 (into regs; no wait)
        if (tt + 2 < NT) {
            loadB(ra, kb + 2 * BKT);
            __builtin_amdgcn_sched_barrier(0);
        }
        // [D] MFMA cluster (A-builds interleave on VALU)
        __builtin_amdgcn_s_setprio(1);
        #pragma unroll
        for (int s = 0; s < 2; s++) {
            #pragma unroll
            for (int mt = 0; mt < MT; mt++) {
                ABFrag af[4];
                #pragma unroll
                for (int mi = 0; mi < 4; mi++) {
                    unsigned int T = (w32v[s][mt] >> (mi * 8 + qh4)) & 0xFu;
                    unsigned int rel = T - sub8;                    // one-hot iff rel in [0,8)
                    unsigned long long sh = 0x3F80ull << ((rel & 3) << 4);  // bf16 1.0
                    af[mi].u[0] = (rel < 4u) ? sh : 0ull;
                    af[mi].u[1] = ((rel - 4u) < 4u) ? sh : 0ull;
                }
                #pragma unroll
                for (int mi = 0; mi < 4; mi++)
                    #pragma unroll
                    for (int ni = 0; ni < 4; ni++)
                        acc[mt][mi][ni] = __builtin_amdgcn_mfma_f32_16x16x32_bf16(
                            af[mi].v, bf2[s][ni].v, acc[mt][mi][ni], 0, 0, 0);
            }
        }
        __builtin_amdgcn_s_setprio(0);
        __builtin_amdgcn_sched_barrier(0);
        // [E] loads (issued pre-cluster) are back; convert + write into cur
        if (tt + 2 < NT) {
            asm volatile("s_waitcnt vmcnt(0)" ::: "memory");
            cvtWrite(cur, ra);
            asm volatile("s_waitcnt lgkmcnt(0)" ::: "memory");
        }
        // [F] tile tt+1 writes (last iter's [E]) ordered before next [A]
        __builtin_amdgcn_s_barrier();
        __builtin_amdgcn_sched_barrier(0);
    }

    // --- epilogue: MFMA row m = q*4 + r -> global row = m0 + mt*128 + wm*64 + 4*m + mi ---
    #pragma unroll
    for (int mt = 0; mt < MT; mt++) {
        #pragma unroll
        for (int mi = 0; mi < 4; mi++) {
            #pragma unroll
            for (int ni = 0; ni < 4; ni++) {
                const int col = n0 + wn * 64 + ni * 16 + l15;
                #pragma unroll
                for (int r = 0; r < 4; r++) {
                    const int row = m0 + mt * 128 + wm * 64 + 4 * (q * 4 + r) + mi;
                    out[(size_t)row * OUT_F + col] = acc[mt][mi][ni][r];
                }
            }
        }
    }
}

extern "C" void kernel_launch(void* const* d_in, const int* in_sizes, int n_in,
                              void* d_out, int out_size, void* d_ws, size_t ws_size,
                              hipStream_t stream) {
    const float* input = (const float*)d_in[0];
    const int*   dims  = (const int*)d_in[1];
    // d_in[2] selection_matrix, d_in[4] tree_des_mat: structure folded into the kernels
    const float* thr   = (const float*)d_in[3];
    const float* lut   = (const float*)d_in[5];
    float* out = (float*)d_out;

    unsigned char* idx4 = (unsigned char*)d_ws;              // 512 KB

    const int nblocks = (OUT_F / BN) * (N_ROWS / (BM * MT)); // 32 x 16 = 512

    k_idx<<<N_ROWS, C_CB, 0, stream>>>(input, dims, thr, idx4);
    k_gemm<<<nblocks, 256, 0, stream>>>(lut, idx4, out);
}